// Round 7
// baseline (202.055 us; speedup 1.0000x reference)
//
#include <hip/hip_runtime.h>

#define N_NODES 50000
#define E_EDGES 800000
#define NE_TOT  (E_EDGES + N_NODES)   // edges + self loops = 850000
#define IND     128
#define HID     64
#define CAP     64                    // max in-degree processed (Poisson(17): P(>=64) ~ 1e-19)
#define NEG_SLOPE 0.2f
#define SCAN_BLKS ((N_NODES + 255) / 256)   // 196

typedef short v8s __attribute__((ext_vector_type(8)));
typedef float v4f __attribute__((ext_vector_type(4)));

// XOR swizzle: spreads stride-256B/128B row reads across 8 16B slots (T2)
#define SWZ(row, byte) ((byte) ^ (((row) & 7) << 4))

static __device__ __forceinline__ unsigned short f2bf(float f) {
    unsigned u = __float_as_uint(f);
    return (unsigned short)((u + 0x7FFF + ((u >> 16) & 1)) >> 16);  // RNE
}
static __device__ __forceinline__ float bf2f(unsigned short u) {
    return __uint_as_float(((unsigned)u) << 16);
}

// ---------------------------------------------------------------- utilities
__global__ void k_zero(int* __restrict__ cnt, float* __restrict__ sums) {
    int i = blockIdx.x * 256 + threadIdx.x;
    if (i < N_NODES) cnt[i] = 0;
    if (i < 128) sums[i] = 0.f;
}

// transpose + bf16-convert weights once: W1T[c][k] (64x128), W2T[c][k] (64x64)
__global__ void k_prep(const float* __restrict__ W1, const float* __restrict__ W2,
                       unsigned short* __restrict__ w1t, unsigned short* __restrict__ w2t) {
    int tid = threadIdx.x;
    for (int idx = tid; idx < 64 * IND; idx += 256) {
        int c = idx >> 7, k = idx & 127;
        w1t[idx] = f2bf(W1[k * 64 + c]);
    }
    for (int idx = tid; idx < 64 * 64; idx += 256) {
        int c = idx >> 6, k = idx & 63;
        w2t[idx] = f2bf(W2[k * 64 + c]);
    }
}

// ---------------------------------------------------------------- CSR build: count / scan / place
__global__ void k_count(const int* __restrict__ ei, int* __restrict__ cnt) {
    int e = blockIdx.x * 256 + threadIdx.x;
    if (e >= NE_TOT) return;
    int d = (e < E_EDGES) ? ei[E_EDGES + e] : (e - E_EDGES);
    atomicAdd(&cnt[d], 1);
}

// block-level exclusive scan of cnt -> rowstart (local), block totals -> bsum
__global__ __launch_bounds__(256) void k_scanA(const int* __restrict__ cnt,
                                               int* __restrict__ rowstart, int* __restrict__ bsum) {
    __shared__ int s[256];
    int tid = threadIdx.x, i = blockIdx.x * 256 + tid;
    int v = (i < N_NODES) ? cnt[i] : 0;
    s[tid] = v;
    __syncthreads();
#pragma unroll
    for (int off = 1; off < 256; off <<= 1) {
        int t = (tid >= off) ? s[tid - off] : 0;
        __syncthreads();
        s[tid] += t;
        __syncthreads();
    }
    if (i < N_NODES) rowstart[i] = s[tid] - v;     // exclusive within block
    if (tid == 255) bsum[blockIdx.x] = s[255];
}

__global__ __launch_bounds__(256) void k_scanB(const int* __restrict__ bsum, int* __restrict__ bpre) {
    __shared__ int s[256];
    int tid = threadIdx.x;
    int v = (tid < SCAN_BLKS) ? bsum[tid] : 0;
    s[tid] = v;
    __syncthreads();
#pragma unroll
    for (int off = 1; off < 256; off <<= 1) {
        int t = (tid >= off) ? s[tid - off] : 0;
        __syncthreads();
        s[tid] += t;
        __syncthreads();
    }
    if (tid < SCAN_BLKS) bpre[tid] = s[tid] - v;   // exclusive block prefix
}

__global__ void k_scanC(int* __restrict__ rowstart, int* __restrict__ rowwork,
                        const int* __restrict__ bpre) {
    int i = blockIdx.x * 256 + threadIdx.x;
    if (i >= N_NODES) return;
    int rs = rowstart[i] + bpre[blockIdx.x];
    rowstart[i] = rs;
    rowwork[i] = rs;
}

__global__ void k_place(const int* __restrict__ ei, int* __restrict__ rowwork,
                        unsigned short* __restrict__ adj) {
    int e = blockIdx.x * 256 + threadIdx.x;
    if (e >= NE_TOT) return;
    int s, d;
    if (e < E_EDGES) { s = ei[e]; d = ei[E_EDGES + e]; }
    else { s = e - E_EDGES; d = s; }               // self loop
    int pos = atomicAdd(&rowwork[d], 1);
    adj[pos] = (unsigned short)s;
}

// ---------------------------------------------------------------- GEMM1 (MFMA bf16): h1 = x @ W1 + dots
__global__ __launch_bounds__(256) void k_gemm1(
    const float* __restrict__ x, const unsigned short* __restrict__ w1t,
    const float* __restrict__ as_w, const float* __restrict__ ad_w,
    unsigned short* __restrict__ hbf, float* __restrict__ as_out, float* __restrict__ ad_out)
{
    __shared__ __align__(16) char sA[64 * 256];   // bf16 [row][k=128], swizzled
    __shared__ __align__(16) char sB[64 * 256];   // bf16 [col][k=128], swizzled
    __shared__ float sAs[64], sAd[64];
    int tid = threadIdx.x;
    int row0 = blockIdx.x * 64;

#pragma unroll
    for (int i = 0; i < 8; ++i) {                  // 2048 float4 (rows = 32 x 8B chunks)
        int idx = i * 256 + tid;
        int r = idx >> 5, c4 = idx & 31;
        int gr = row0 + r; if (gr >= N_NODES) gr = N_NODES - 1;
        float4 v = ((const float4*)(x + (size_t)gr * IND))[c4];
        ushort4 b; b.x = f2bf(v.x); b.y = f2bf(v.y); b.z = f2bf(v.z); b.w = f2bf(v.w);
        *(ushort4*)(sA + r * 256 + SWZ(r, c4 * 8)) = b;
    }
#pragma unroll
    for (int i = 0; i < 4; ++i) {                  // 1024 x 16B (rows = 16 x 16B chunks)
        int idx = i * 256 + tid;
        int r = idx >> 4, c8 = idx & 15;
        v8s wv = *(const v8s*)(w1t + idx * 8);
        *(v8s*)(sB + r * 256 + SWZ(r, c8 * 16)) = wv;
    }
    if (tid < 64) { sAs[tid] = as_w[tid]; sAd[tid] = ad_w[tid]; }
    __syncthreads();

    int w = tid >> 6, lane = tid & 63;
    int arow = w * 16 + (lane & 15);
    int kb   = (lane >> 4) * 16;
    v4f acc[4] = {};
#pragma unroll
    for (int ks = 0; ks < 4; ++ks) {
        v8s a = *(const v8s*)(sA + arow * 256 + SWZ(arow, ks * 64 + kb));
#pragma unroll
        for (int ct = 0; ct < 4; ++ct) {
            int brow = ct * 16 + (lane & 15);
            v8s b = *(const v8s*)(sB + brow * 256 + SWZ(brow, ks * 64 + kb));
            acc[ct] = __builtin_amdgcn_mfma_f32_16x16x32_bf16(a, b, acc[ct], 0, 0, 0);
        }
    }

    int cbase = lane & 15;
    int rloc  = (lane >> 4) * 4;
#pragma unroll
    for (int ct = 0; ct < 4; ++ct)
#pragma unroll
        for (int rg = 0; rg < 4; ++rg) {
            int row = row0 + w * 16 + rloc + rg;
            if (row < N_NODES) hbf[(size_t)row * 64 + ct * 16 + cbase] = f2bf(acc[ct][rg]);
        }
#pragma unroll
    for (int rg = 0; rg < 4; ++rg) {
        float vs = 0.f, vd = 0.f;
#pragma unroll
        for (int ct = 0; ct < 4; ++ct) {
            vs = fmaf(acc[ct][rg], sAs[ct * 16 + cbase], vs);
            vd = fmaf(acc[ct][rg], sAd[ct * 16 + cbase], vd);
        }
        vs += __shfl_xor(vs, 1, 64); vd += __shfl_xor(vd, 1, 64);
        vs += __shfl_xor(vs, 2, 64); vd += __shfl_xor(vd, 2, 64);
        vs += __shfl_xor(vs, 4, 64); vd += __shfl_xor(vd, 4, 64);
        vs += __shfl_xor(vs, 8, 64); vd += __shfl_xor(vd, 8, 64);
        int row = row0 + w * 16 + rloc + rg;
        if (cbase == 0 && row < N_NODES) { as_out[row] = vs; ad_out[row] = vd; }
    }
}

// ---------------------------------------------------------------- per-dst softmax aggregation (CSR)
__global__ __launch_bounds__(256) void k_agg(
    const unsigned short* __restrict__ hin, const float* __restrict__ as_, const float* __restrict__ ad_,
    const int* __restrict__ rowstart, const int* __restrict__ cnt, const unsigned short* __restrict__ adj,
    const float* __restrict__ bias, float* __restrict__ out)
{
    int wave = threadIdx.x >> 6, lane = threadIdx.x & 63;
    int n = blockIdx.x * 4 + wave;
    if (n >= N_NODES) return;
    int deg = min(cnt[n], CAP);
    int start = rowstart[n];
    float adn = ad_[n];

    int s_l = 0;
    float e = -1e30f;
    if (lane < deg) {
        s_l = (int)adj[start + lane];              // contiguous 128B per node
        float t = as_[s_l] + adn;
        e = t > 0.f ? t : NEG_SLOPE * t;
    }
    float m = e;
    for (int off = 32; off; off >>= 1) m = fmaxf(m, __shfl_xor(m, off, 64));
    float w_l = (lane < deg) ? __expf(e - m) : 0.f;
    float denom = w_l;
    for (int off = 32; off; off >>= 1) denom += __shfl_xor(denom, off, 64);

    float acc = 0.f;
    for (int t = 0; t < deg; t += 8) {
        int s0 = __shfl(s_l, t + 0), s1 = __shfl(s_l, t + 1);
        int s2 = __shfl(s_l, t + 2), s3 = __shfl(s_l, t + 3);
        int s4 = __shfl(s_l, t + 4), s5 = __shfl(s_l, t + 5);
        int s6 = __shfl(s_l, t + 6), s7 = __shfl(s_l, t + 7);
        float w0 = __shfl(w_l, t + 0), w1 = __shfl(w_l, t + 1);
        float w2 = __shfl(w_l, t + 2), w3 = __shfl(w_l, t + 3);
        float w4 = __shfl(w_l, t + 4), w5 = __shfl(w_l, t + 5);
        float w6 = __shfl(w_l, t + 6), w7 = __shfl(w_l, t + 7);
        float v0 = bf2f(hin[(size_t)s0 * HID + lane]);
        float v1 = bf2f(hin[(size_t)s1 * HID + lane]);
        float v2 = bf2f(hin[(size_t)s2 * HID + lane]);
        float v3 = bf2f(hin[(size_t)s3 * HID + lane]);
        float v4 = bf2f(hin[(size_t)s4 * HID + lane]);
        float v5 = bf2f(hin[(size_t)s5 * HID + lane]);
        float v6 = bf2f(hin[(size_t)s6 * HID + lane]);
        float v7 = bf2f(hin[(size_t)s7 * HID + lane]);
        acc = fmaf(w0, v0, acc); acc = fmaf(w1, v1, acc);
        acc = fmaf(w2, v2, acc); acc = fmaf(w3, v3, acc);
        acc = fmaf(w4, v4, acc); acc = fmaf(w5, v5, acc);
        acc = fmaf(w6, v6, acc); acc = fmaf(w7, v7, acc);
    }
    float inv = 1.f / (denom + 1e-16f);
    out[(size_t)n * HID + lane] = acc * inv + bias[lane];
}

// ---------------------------------------------------------------- BN statistics (two-stage)
__global__ __launch_bounds__(256) void k_bnstats(const float* __restrict__ h, float* __restrict__ sums) {
    int lane = threadIdx.x & 63, wave = threadIdx.x >> 6;
    float s = 0.f, ss = 0.f;
    for (int r = blockIdx.x * 4 + wave; r < N_NODES; r += gridDim.x * 4) {
        float v = h[(size_t)r * HID + lane];
        s += v; ss = fmaf(v, v, ss);
    }
    __shared__ float ls[4][64], lss[4][64];
    ls[wave][lane] = s; lss[wave][lane] = ss;
    __syncthreads();
    if (wave == 0) {
        s  = ls[0][lane] + ls[1][lane] + ls[2][lane] + ls[3][lane];
        ss = lss[0][lane] + lss[1][lane] + lss[2][lane] + lss[3][lane];
        atomicAdd(&sums[lane], s);
        atomicAdd(&sums[64 + lane], ss);
    }
}

__global__ void k_bnfinal(const float* __restrict__ sums, const float* __restrict__ gamma,
                          const float* __restrict__ beta, float* __restrict__ ss_out) {
    int j = threadIdx.x;
    if (j >= 64) return;
    float mean = sums[j] * (1.f / N_NODES);
    float var  = sums[64 + j] * (1.f / N_NODES) - mean * mean;
    float sc = gamma[j] * rsqrtf(var + 1e-5f);
    ss_out[j] = sc;
    ss_out[64 + j] = beta[j] - mean * sc;
}

// ---------------------------------------------------------------- GEMM2 (MFMA bf16), BN+ReLU fused
__global__ __launch_bounds__(256) void k_gemm2(
    const float* __restrict__ hin, const unsigned short* __restrict__ w2t,
    const float* __restrict__ ss,
    const float* __restrict__ as_w, const float* __restrict__ ad_w,
    unsigned short* __restrict__ h2bf, float* __restrict__ as_out, float* __restrict__ ad_out)
{
    __shared__ __align__(16) char sA[64 * 128];   // bf16 [row][k=64], swizzled
    __shared__ __align__(16) char sB[64 * 128];   // bf16 [col][k=64], swizzled
    __shared__ float sAs[64], sAd[64];
    int tid = threadIdx.x;
    int row0 = blockIdx.x * 64;

#pragma unroll
    for (int i = 0; i < 4; ++i) {                  // 1024 float4 (rows = 16 x 8B chunks)
        int idx = i * 256 + tid;
        int r = idx >> 4, c4 = idx & 15;
        int gr = row0 + r; if (gr >= N_NODES) gr = N_NODES - 1;
        float4 v  = ((const float4*)(hin + (size_t)gr * 64))[c4];
        float4 sc = ((const float4*)ss)[c4];
        float4 sh = ((const float4*)(ss + 64))[c4];
        ushort4 b;
        b.x = f2bf(fmaxf(fmaf(v.x, sc.x, sh.x), 0.f));
        b.y = f2bf(fmaxf(fmaf(v.y, sc.y, sh.y), 0.f));
        b.z = f2bf(fmaxf(fmaf(v.z, sc.z, sh.z), 0.f));
        b.w = f2bf(fmaxf(fmaf(v.w, sc.w, sh.w), 0.f));
        *(ushort4*)(sA + r * 128 + SWZ(r, c4 * 8)) = b;
    }
#pragma unroll
    for (int i = 0; i < 2; ++i) {                  // 512 x 16B (rows = 8 x 16B chunks)
        int idx = i * 256 + tid;
        int r = idx >> 3, c8 = idx & 7;
        v8s wv = *(const v8s*)(w2t + idx * 8);
        *(v8s*)(sB + r * 128 + SWZ(r, c8 * 16)) = wv;
    }
    if (tid < 64) { sAs[tid] = as_w[tid]; sAd[tid] = ad_w[tid]; }
    __syncthreads();

    int w = tid >> 6, lane = tid & 63;
    int arow = w * 16 + (lane & 15);
    int kb   = (lane >> 4) * 16;
    v4f acc[4] = {};
#pragma unroll
    for (int ks = 0; ks < 2; ++ks) {
        v8s a = *(const v8s*)(sA + arow * 128 + SWZ(arow, ks * 64 + kb));
#pragma unroll
        for (int ct = 0; ct < 4; ++ct) {
            int brow = ct * 16 + (lane & 15);
            v8s b = *(const v8s*)(sB + brow * 128 + SWZ(brow, ks * 64 + kb));
            acc[ct] = __builtin_amdgcn_mfma_f32_16x16x32_bf16(a, b, acc[ct], 0, 0, 0);
        }
    }

    int cbase = lane & 15;
    int rloc  = (lane >> 4) * 4;
#pragma unroll
    for (int ct = 0; ct < 4; ++ct)
#pragma unroll
        for (int rg = 0; rg < 4; ++rg) {
            int row = row0 + w * 16 + rloc + rg;
            if (row < N_NODES) h2bf[(size_t)row * 64 + ct * 16 + cbase] = f2bf(acc[ct][rg]);
        }
#pragma unroll
    for (int rg = 0; rg < 4; ++rg) {
        float vs = 0.f, vd = 0.f;
#pragma unroll
        for (int ct = 0; ct < 4; ++ct) {
            vs = fmaf(acc[ct][rg], sAs[ct * 16 + cbase], vs);
            vd = fmaf(acc[ct][rg], sAd[ct * 16 + cbase], vd);
        }
        vs += __shfl_xor(vs, 1, 64); vd += __shfl_xor(vd, 1, 64);
        vs += __shfl_xor(vs, 2, 64); vd += __shfl_xor(vd, 2, 64);
        vs += __shfl_xor(vs, 4, 64); vd += __shfl_xor(vd, 4, 64);
        vs += __shfl_xor(vs, 8, 64); vd += __shfl_xor(vd, 8, 64);
        int row = row0 + w * 16 + rloc + rg;
        if (cbase == 0 && row < N_NODES) { as_out[row] = vs; ad_out[row] = vd; }
    }
}

// ---------------------------------------------------------------- launch
extern "C" void kernel_launch(void* const* d_in, const int* in_sizes, int n_in,
                              void* d_out, int out_size, void* d_ws, size_t ws_size,
                              hipStream_t stream) {
    const float* x        = (const float*)d_in[0];
    const int*   ei       = (const int*)d_in[1];
    const float* W1       = (const float*)d_in[2];
    const float* att_src1 = (const float*)d_in[3];
    const float* att_dst1 = (const float*)d_in[4];
    const float* bias1    = (const float*)d_in[5];
    const float* gamma    = (const float*)d_in[6];
    const float* beta     = (const float*)d_in[7];
    const float* W2       = (const float*)d_in[8];
    const float* att_src2 = (const float*)d_in[9];
    const float* att_dst2 = (const float*)d_in[10];
    const float* bias2    = (const float*)d_in[11];
    float* out = (float*)d_out;

    char* ws = (char*)d_ws;
    size_t off = 0;
    auto alloc = [&](size_t bytes) { void* p = ws + off; off = (off + bytes + 255) & ~(size_t)255; return p; };
    unsigned short* h1 = (unsigned short*)alloc((size_t)N_NODES * HID * 2);
    float* as1    = (float*)alloc((size_t)N_NODES * 4);
    float* ad1    = (float*)alloc((size_t)N_NODES * 4);
    float* h1agg  = (float*)alloc((size_t)N_NODES * HID * 4);
    unsigned short* h2 = (unsigned short*)alloc((size_t)N_NODES * HID * 2);
    float* as2    = (float*)alloc((size_t)N_NODES * 4);
    float* ad2    = (float*)alloc((size_t)N_NODES * 4);
    int*   cnt      = (int*)alloc((size_t)N_NODES * 4);
    int*   rowstart = (int*)alloc((size_t)N_NODES * 4);
    int*   rowwork  = (int*)alloc((size_t)N_NODES * 4);
    int*   bsum     = (int*)alloc(256 * 4);
    int*   bpre     = (int*)alloc(256 * 4);
    unsigned short* adj = (unsigned short*)alloc((size_t)(NE_TOT + 64) * 2);
    float* sums   = (float*)alloc(128 * 4);
    float* bn_ss  = (float*)alloc(128 * 4);
    unsigned short* w1t = (unsigned short*)alloc(64 * IND * 2);
    unsigned short* w2t = (unsigned short*)alloc(64 * 64 * 2);

    int gemmBlocks = (N_NODES + 63) / 64;   // 782
    int edgeBlocks = (NE_TOT + 255) / 256;  // 3321
    k_zero<<<(N_NODES + 255) / 256, 256, 0, stream>>>(cnt, sums);
    k_prep<<<1, 256, 0, stream>>>(W1, W2, w1t, w2t);
    k_count<<<edgeBlocks, 256, 0, stream>>>(ei, cnt);
    k_scanA<<<SCAN_BLKS, 256, 0, stream>>>(cnt, rowstart, bsum);
    k_scanB<<<1, 256, 0, stream>>>(bsum, bpre);
    k_scanC<<<SCAN_BLKS, 256, 0, stream>>>(rowstart, rowwork, bpre);
    k_place<<<edgeBlocks, 256, 0, stream>>>(ei, rowwork, adj);
    k_gemm1<<<gemmBlocks, 256, 0, stream>>>(x, w1t, att_src1, att_dst1, h1, as1, ad1);
    k_agg<<<(N_NODES + 3) / 4, 256, 0, stream>>>(h1, as1, ad1, rowstart, cnt, adj, bias1, h1agg);
    k_bnstats<<<256, 256, 0, stream>>>(h1agg, sums);
    k_bnfinal<<<1, 64, 0, stream>>>(sums, gamma, beta, bn_ss);
    k_gemm2<<<gemmBlocks, 256, 0, stream>>>(h1agg, w2t, bn_ss, att_src2, att_dst2, h2, as2, ad2);
    k_agg<<<(N_NODES + 3) / 4, 256, 0, stream>>>(h2, as2, ad2, rowstart, cnt, adj, bias2, out);
}

// Round 8
// 145.089 us; speedup vs baseline: 1.3926x; 1.3926x over previous
//
#include <hip/hip_runtime.h>

#define N_NODES 50000
#define E_EDGES 800000
#define NE_TOT  (E_EDGES + N_NODES)   // edges + self loops = 850000
#define IND     128
#define HID     64
#define CAP_X   32                    // per-XCD slot cap (per-XCD deg ~ Poisson(2.1))
#define NEG_SLOPE 0.2f

typedef short v8s __attribute__((ext_vector_type(8)));
typedef float v4f __attribute__((ext_vector_type(4)));

// XOR swizzle: spreads stride-256B/128B row reads across 8 16B slots (T2)
#define SWZ(row, byte) ((byte) ^ (((row) & 7) << 4))

static __device__ __forceinline__ unsigned short f2bf(float f) {
    unsigned u = __float_as_uint(f);
    return (unsigned short)((u + 0x7FFF + ((u >> 16) & 1)) >> 16);  // RNE
}
static __device__ __forceinline__ float bf2f(unsigned short u) {
    return __uint_as_float(((unsigned)u) << 16);
}

// ---------------------------------------------------------------- init: zero cnt/sums + prep weights
__global__ void k_init(const float* __restrict__ W1, const float* __restrict__ W2,
                       int* __restrict__ cnt, float* __restrict__ sums,
                       unsigned short* __restrict__ w1t, unsigned short* __restrict__ w2t) {
    int g = blockIdx.x * 256 + threadIdx.x;
    if (g < 8 * N_NODES) cnt[g] = 0;
    if (g < 128) sums[g] = 0.f;
    if (g < 64 * IND) { int c = g >> 7, k = g & 127; w1t[g] = f2bf(W1[k * 64 + c]); }
    if (g < 64 * 64)  { int c = g >> 6, k = g & 63;  w2t[g] = f2bf(W2[k * 64 + c]); }
}

// ---------------------------------------------------------------- scatter into XCD-private buckets
// Physical chiplet id via hwreg 20 (HW_REG_XCC_ID, gfx940+). Each XCD writes only
// its own cnt/bucket segment -> no cross-XCD line sharing, single writeback.
// Correct for ANY xcc value in [0,8): agg sums all 8 segments.
__global__ void k_scatter(const int* __restrict__ ei, int* __restrict__ cnt,
                          unsigned short* __restrict__ bucket) {
    int xcc;
    asm("s_getreg_b32 %0, hwreg(20, 0, 32)" : "=s"(xcc));
    xcc &= 7;
    int e = blockIdx.x * 256 + threadIdx.x;
    if (e >= NE_TOT) return;
    int s, d;
    if (e < E_EDGES) { s = ei[e]; d = ei[E_EDGES + e]; }
    else { s = d = e - E_EDGES; }                  // self loop
    int pos = atomicAdd(&cnt[xcc * N_NODES + d], 1);
    if (pos < CAP_X) bucket[((size_t)(xcc * CAP_X + pos)) * N_NODES + d] = (unsigned short)s;
}

// ---------------------------------------------------------------- GEMM1 (MFMA bf16): h1 = x @ W1 + dots
__global__ __launch_bounds__(256) void k_gemm1(
    const float* __restrict__ x, const unsigned short* __restrict__ w1t,
    const float* __restrict__ as_w, const float* __restrict__ ad_w,
    unsigned short* __restrict__ hbf, float* __restrict__ as_out, float* __restrict__ ad_out)
{
    __shared__ __align__(16) char sA[64 * 256];   // bf16 [row][k=128], swizzled
    __shared__ __align__(16) char sB[64 * 256];   // bf16 [col][k=128], swizzled
    __shared__ float sAs[64], sAd[64];
    int tid = threadIdx.x;
    int row0 = blockIdx.x * 64;

#pragma unroll
    for (int i = 0; i < 8; ++i) {                  // 2048 float4 (rows = 32 x 8B chunks)
        int idx = i * 256 + tid;
        int r = idx >> 5, c4 = idx & 31;
        int gr = row0 + r; if (gr >= N_NODES) gr = N_NODES - 1;
        float4 v = ((const float4*)(x + (size_t)gr * IND))[c4];
        ushort4 b; b.x = f2bf(v.x); b.y = f2bf(v.y); b.z = f2bf(v.z); b.w = f2bf(v.w);
        *(ushort4*)(sA + r * 256 + SWZ(r, c4 * 8)) = b;
    }
#pragma unroll
    for (int i = 0; i < 4; ++i) {                  // 1024 x 16B (rows = 16 x 16B chunks)
        int idx = i * 256 + tid;
        int r = idx >> 4, c8 = idx & 15;
        v8s wv = *(const v8s*)(w1t + idx * 8);
        *(v8s*)(sB + r * 256 + SWZ(r, c8 * 16)) = wv;
    }
    if (tid < 64) { sAs[tid] = as_w[tid]; sAd[tid] = ad_w[tid]; }
    __syncthreads();

    int w = tid >> 6, lane = tid & 63;
    int arow = w * 16 + (lane & 15);
    int kb   = (lane >> 4) * 16;
    v4f acc[4] = {};
#pragma unroll
    for (int ks = 0; ks < 4; ++ks) {
        v8s a = *(const v8s*)(sA + arow * 256 + SWZ(arow, ks * 64 + kb));
#pragma unroll
        for (int ct = 0; ct < 4; ++ct) {
            int brow = ct * 16 + (lane & 15);
            v8s b = *(const v8s*)(sB + brow * 256 + SWZ(brow, ks * 64 + kb));
            acc[ct] = __builtin_amdgcn_mfma_f32_16x16x32_bf16(a, b, acc[ct], 0, 0, 0);
        }
    }

    int cbase = lane & 15;
    int rloc  = (lane >> 4) * 4;
#pragma unroll
    for (int ct = 0; ct < 4; ++ct)
#pragma unroll
        for (int rg = 0; rg < 4; ++rg) {
            int row = row0 + w * 16 + rloc + rg;
            if (row < N_NODES) hbf[(size_t)row * 64 + ct * 16 + cbase] = f2bf(acc[ct][rg]);
        }
#pragma unroll
    for (int rg = 0; rg < 4; ++rg) {
        float vs = 0.f, vd = 0.f;
#pragma unroll
        for (int ct = 0; ct < 4; ++ct) {
            vs = fmaf(acc[ct][rg], sAs[ct * 16 + cbase], vs);
            vd = fmaf(acc[ct][rg], sAd[ct * 16 + cbase], vd);
        }
        vs += __shfl_xor(vs, 1, 64); vd += __shfl_xor(vd, 1, 64);
        vs += __shfl_xor(vs, 2, 64); vd += __shfl_xor(vd, 2, 64);
        vs += __shfl_xor(vs, 4, 64); vd += __shfl_xor(vd, 4, 64);
        vs += __shfl_xor(vs, 8, 64); vd += __shfl_xor(vd, 8, 64);
        int row = row0 + w * 16 + rloc + rg;
        if (cbase == 0 && row < N_NODES) { as_out[row] = vs; ad_out[row] = vd; }
    }
}

// ---------------------------------------------------------------- per-dst softmax aggregation
// Merges the 8 XCD-private segments via an in-register 8-entry prefix (static idx).
template <bool OUT_BF16>
__global__ __launch_bounds__(256) void k_agg(
    const unsigned short* __restrict__ hin, const float* __restrict__ as_, const float* __restrict__ ad_,
    const int* __restrict__ cnt, const unsigned short* __restrict__ bucket,
    const float* __restrict__ bias, void* __restrict__ outv)
{
    int wave = threadIdx.x >> 6, lane = threadIdx.x & 63;
    int n = blockIdx.x * 4 + wave;
    if (n >= N_NODES) return;

    int pref[9]; pref[0] = 0;
#pragma unroll
    for (int xx = 0; xx < 8; ++xx)
        pref[xx + 1] = pref[xx] + min(cnt[xx * N_NODES + n], CAP_X);
    int deg = min(pref[8], 64);

    int xseg = 0, base = 0;
#pragma unroll
    for (int i = 0; i < 7; ++i)
        if (lane >= pref[i + 1]) { xseg = i + 1; base = pref[i + 1]; }

    float adn = ad_[n];
    int s_l = 0;
    float e = -1e30f;
    if (lane < deg) {
        s_l = (int)bucket[((size_t)(xseg * CAP_X + (lane - base))) * N_NODES + n];
        float t = as_[s_l] + adn;
        e = t > 0.f ? t : NEG_SLOPE * t;
    }
    float m = e;
    for (int off = 32; off; off >>= 1) m = fmaxf(m, __shfl_xor(m, off, 64));
    float w_l = (lane < deg) ? __expf(e - m) : 0.f;
    float denom = w_l;
    for (int off = 32; off; off >>= 1) denom += __shfl_xor(denom, off, 64);

    float acc = 0.f;
    for (int t = 0; t < deg; t += 8) {
        int s0 = __shfl(s_l, t + 0), s1 = __shfl(s_l, t + 1);
        int s2 = __shfl(s_l, t + 2), s3 = __shfl(s_l, t + 3);
        int s4 = __shfl(s_l, t + 4), s5 = __shfl(s_l, t + 5);
        int s6 = __shfl(s_l, t + 6), s7 = __shfl(s_l, t + 7);
        float w0 = __shfl(w_l, t + 0), w1 = __shfl(w_l, t + 1);
        float w2 = __shfl(w_l, t + 2), w3 = __shfl(w_l, t + 3);
        float w4 = __shfl(w_l, t + 4), w5 = __shfl(w_l, t + 5);
        float w6 = __shfl(w_l, t + 6), w7 = __shfl(w_l, t + 7);
        float v0 = bf2f(hin[(size_t)s0 * HID + lane]);
        float v1 = bf2f(hin[(size_t)s1 * HID + lane]);
        float v2 = bf2f(hin[(size_t)s2 * HID + lane]);
        float v3 = bf2f(hin[(size_t)s3 * HID + lane]);
        float v4 = bf2f(hin[(size_t)s4 * HID + lane]);
        float v5 = bf2f(hin[(size_t)s5 * HID + lane]);
        float v6 = bf2f(hin[(size_t)s6 * HID + lane]);
        float v7 = bf2f(hin[(size_t)s7 * HID + lane]);
        acc = fmaf(w0, v0, acc); acc = fmaf(w1, v1, acc);
        acc = fmaf(w2, v2, acc); acc = fmaf(w3, v3, acc);
        acc = fmaf(w4, v4, acc); acc = fmaf(w5, v5, acc);
        acc = fmaf(w6, v6, acc); acc = fmaf(w7, v7, acc);
    }
    float inv = 1.f / (denom + 1e-16f);
    float res = acc * inv + bias[lane];
    if (OUT_BF16) ((unsigned short*)outv)[(size_t)n * HID + lane] = f2bf(res);
    else          ((float*)outv)[(size_t)n * HID + lane] = res;
}

// ---------------------------------------------------------------- BN statistics (two-stage, bf16 in)
__global__ __launch_bounds__(256) void k_bnstats(const unsigned short* __restrict__ h,
                                                 float* __restrict__ sums) {
    int lane = threadIdx.x & 63, wave = threadIdx.x >> 6;
    float s = 0.f, ss = 0.f;
    for (int r = blockIdx.x * 4 + wave; r < N_NODES; r += gridDim.x * 4) {
        float v = bf2f(h[(size_t)r * HID + lane]);
        s += v; ss = fmaf(v, v, ss);
    }
    __shared__ float ls[4][64], lss[4][64];
    ls[wave][lane] = s; lss[wave][lane] = ss;
    __syncthreads();
    if (wave == 0) {
        s  = ls[0][lane] + ls[1][lane] + ls[2][lane] + ls[3][lane];
        ss = lss[0][lane] + lss[1][lane] + lss[2][lane] + lss[3][lane];
        atomicAdd(&sums[lane], s);
        atomicAdd(&sums[64 + lane], ss);
    }
}

__global__ void k_bnfinal(const float* __restrict__ sums, const float* __restrict__ gamma,
                          const float* __restrict__ beta, float* __restrict__ ss_out) {
    int j = threadIdx.x;
    if (j >= 64) return;
    float mean = sums[j] * (1.f / N_NODES);
    float var  = sums[64 + j] * (1.f / N_NODES) - mean * mean;
    float sc = gamma[j] * rsqrtf(var + 1e-5f);
    ss_out[j] = sc;
    ss_out[64 + j] = beta[j] - mean * sc;
}

// ---------------------------------------------------------------- GEMM2 (MFMA bf16), BN+ReLU fused, bf16 in
__global__ __launch_bounds__(256) void k_gemm2(
    const unsigned short* __restrict__ hin, const unsigned short* __restrict__ w2t,
    const float* __restrict__ ss,
    const float* __restrict__ as_w, const float* __restrict__ ad_w,
    unsigned short* __restrict__ h2bf, float* __restrict__ as_out, float* __restrict__ ad_out)
{
    __shared__ __align__(16) char sA[64 * 128];   // bf16 [row][k=64], swizzled
    __shared__ __align__(16) char sB[64 * 128];   // bf16 [col][k=64], swizzled
    __shared__ float sAs[64], sAd[64];
    int tid = threadIdx.x;
    int row0 = blockIdx.x * 64;

    // stage input tile (bf16) with BN+ReLU  (rows = 128B = 8 x 16B chunks)
#pragma unroll
    for (int i = 0; i < 2; ++i) {                  // 512 x 16B
        int idx = i * 256 + tid;
        int r = idx >> 3, c8 = idx & 7;
        int gr = row0 + r; if (gr >= N_NODES) gr = N_NODES - 1;
        v8s hv = *(const v8s*)(hin + (size_t)gr * 64 + c8 * 8);
        unsigned short o[8];
#pragma unroll
        for (int j = 0; j < 8; ++j) {
            float f = bf2f((unsigned short)hv[j]);
            float sc = ss[c8 * 8 + j], sh = ss[64 + c8 * 8 + j];
            o[j] = f2bf(fmaxf(fmaf(f, sc, sh), 0.f));
        }
        *(v8s*)(sA + r * 128 + SWZ(r, c8 * 16)) = *(v8s*)o;
    }
    // stage W2T  (rows = 128B = 8 x 16B chunks)
#pragma unroll
    for (int i = 0; i < 2; ++i) {                  // 512 x 16B
        int idx = i * 256 + tid;
        int r = idx >> 3, c8 = idx & 7;
        v8s wv = *(const v8s*)(w2t + idx * 8);
        *(v8s*)(sB + r * 128 + SWZ(r, c8 * 16)) = wv;
    }
    if (tid < 64) { sAs[tid] = as_w[tid]; sAd[tid] = ad_w[tid]; }
    __syncthreads();

    int w = tid >> 6, lane = tid & 63;
    int arow = w * 16 + (lane & 15);
    int kb   = (lane >> 4) * 16;
    v4f acc[4] = {};
#pragma unroll
    for (int ks = 0; ks < 2; ++ks) {
        v8s a = *(const v8s*)(sA + arow * 128 + SWZ(arow, ks * 64 + kb));
#pragma unroll
        for (int ct = 0; ct < 4; ++ct) {
            int brow = ct * 16 + (lane & 15);
            v8s b = *(const v8s*)(sB + brow * 128 + SWZ(brow, ks * 64 + kb));
            acc[ct] = __builtin_amdgcn_mfma_f32_16x16x32_bf16(a, b, acc[ct], 0, 0, 0);
        }
    }

    int cbase = lane & 15;
    int rloc  = (lane >> 4) * 4;
#pragma unroll
    for (int ct = 0; ct < 4; ++ct)
#pragma unroll
        for (int rg = 0; rg < 4; ++rg) {
            int row = row0 + w * 16 + rloc + rg;
            if (row < N_NODES) h2bf[(size_t)row * 64 + ct * 16 + cbase] = f2bf(acc[ct][rg]);
        }
#pragma unroll
    for (int rg = 0; rg < 4; ++rg) {
        float vs = 0.f, vd = 0.f;
#pragma unroll
        for (int ct = 0; ct < 4; ++ct) {
            vs = fmaf(acc[ct][rg], sAs[ct * 16 + cbase], vs);
            vd = fmaf(acc[ct][rg], sAd[ct * 16 + cbase], vd);
        }
        vs += __shfl_xor(vs, 1, 64); vd += __shfl_xor(vd, 1, 64);
        vs += __shfl_xor(vs, 2, 64); vd += __shfl_xor(vd, 2, 64);
        vs += __shfl_xor(vs, 4, 64); vd += __shfl_xor(vd, 4, 64);
        vs += __shfl_xor(vs, 8, 64); vd += __shfl_xor(vd, 8, 64);
        int row = row0 + w * 16 + rloc + rg;
        if (cbase == 0 && row < N_NODES) { as_out[row] = vs; ad_out[row] = vd; }
    }
}

// ---------------------------------------------------------------- launch
extern "C" void kernel_launch(void* const* d_in, const int* in_sizes, int n_in,
                              void* d_out, int out_size, void* d_ws, size_t ws_size,
                              hipStream_t stream) {
    const float* x        = (const float*)d_in[0];
    const int*   ei       = (const int*)d_in[1];
    const float* W1       = (const float*)d_in[2];
    const float* att_src1 = (const float*)d_in[3];
    const float* att_dst1 = (const float*)d_in[4];
    const float* bias1    = (const float*)d_in[5];
    const float* gamma    = (const float*)d_in[6];
    const float* beta     = (const float*)d_in[7];
    const float* W2       = (const float*)d_in[8];
    const float* att_src2 = (const float*)d_in[9];
    const float* att_dst2 = (const float*)d_in[10];
    const float* bias2    = (const float*)d_in[11];
    float* out = (float*)d_out;

    char* ws = (char*)d_ws;
    size_t off = 0;
    auto alloc = [&](size_t bytes) { void* p = ws + off; off = (off + bytes + 255) & ~(size_t)255; return p; };
    unsigned short* h1     = (unsigned short*)alloc((size_t)N_NODES * HID * 2);
    float* as1    = (float*)alloc((size_t)N_NODES * 4);
    float* ad1    = (float*)alloc((size_t)N_NODES * 4);
    unsigned short* h1agg  = (unsigned short*)alloc((size_t)N_NODES * HID * 2);
    unsigned short* h2     = (unsigned short*)alloc((size_t)N_NODES * HID * 2);
    float* as2    = (float*)alloc((size_t)N_NODES * 4);
    float* ad2    = (float*)alloc((size_t)N_NODES * 4);
    int*   cnt    = (int*)alloc((size_t)8 * N_NODES * 4);
    unsigned short* bucket = (unsigned short*)alloc((size_t)8 * CAP_X * N_NODES * 2);
    float* sums   = (float*)alloc(128 * 4);
    float* bn_ss  = (float*)alloc(128 * 4);
    unsigned short* w1t = (unsigned short*)alloc(64 * IND * 2);
    unsigned short* w2t = (unsigned short*)alloc(64 * 64 * 2);

    int gemmBlocks = (N_NODES + 63) / 64;       // 782
    int edgeBlocks = (NE_TOT + 255) / 256;      // 3321
    int initBlocks = (8 * N_NODES + 255) / 256; // 1563
    k_init<<<initBlocks, 256, 0, stream>>>(W1, W2, cnt, sums, w1t, w2t);
    k_gemm1<<<gemmBlocks, 256, 0, stream>>>(x, w1t, att_src1, att_dst1, h1, as1, ad1);
    k_scatter<<<edgeBlocks, 256, 0, stream>>>(ei, cnt, bucket);
    k_agg<true><<<(N_NODES + 3) / 4, 256, 0, stream>>>(h1, as1, ad1, cnt, bucket, bias1, h1agg);
    k_bnstats<<<256, 256, 0, stream>>>(h1agg, sums);
    k_bnfinal<<<1, 64, 0, stream>>>(sums, gamma, beta, bn_ss);
    k_gemm2<<<gemmBlocks, 256, 0, stream>>>(h1agg, w2t, bn_ss, att_src2, att_dst2, h2, as2, ad2);
    k_agg<false><<<(N_NODES + 3) / 4, 256, 0, stream>>>(h2, as2, ad2, cnt, bucket, bias2, out);
}

// Round 9
// 137.442 us; speedup vs baseline: 1.4701x; 1.0556x over previous
//
#include <hip/hip_runtime.h>

#define N_NODES 50000
#define E_EDGES 800000
#define NE_TOT  (E_EDGES + N_NODES)   // edges + self loops = 850000
#define IND     128
#define HID     64
#define CAP_X   32                    // per-XCD slot cap (per-XCD deg ~ Poisson(2.1))
#define NEG_SLOPE 0.2f
#define GEMM_BLKS ((N_NODES + 63) / 64)     // 782
#define EDGE_BLKS ((NE_TOT + 255) / 256)    // 3321

typedef short v8s __attribute__((ext_vector_type(8)));
typedef float v4f __attribute__((ext_vector_type(4)));

// XOR swizzle: spreads stride-256B/128B row reads across 8 16B slots (T2)
#define SWZ(row, byte) ((byte) ^ (((row) & 7) << 4))

static __device__ __forceinline__ unsigned short f2bf(float f) {
    unsigned u = __float_as_uint(f);
    return (unsigned short)((u + 0x7FFF + ((u >> 16) & 1)) >> 16);  // RNE
}
static __device__ __forceinline__ float bf2f(unsigned short u) {
    return __uint_as_float(((unsigned)u) << 16);
}

// ---------------------------------------------------------------- init: zero cnt/sums + prep weights
__global__ void k_init(const float* __restrict__ W1, const float* __restrict__ W2,
                       int* __restrict__ cnt, float* __restrict__ sums,
                       unsigned short* __restrict__ w1t, unsigned short* __restrict__ w2t) {
    int g = blockIdx.x * 256 + threadIdx.x;
    if (g < 8 * N_NODES) cnt[g] = 0;
    if (g < 128) sums[g] = 0.f;
    if (g < 64 * IND) { int c = g >> 7, k = g & 127; w1t[g] = f2bf(W1[k * 64 + c]); }
    if (g < 64 * 64)  { int c = g >> 6, k = g & 63;  w2t[g] = f2bf(W2[k * 64 + c]); }
}

// ---------------------------------------------------------------- fused GEMM1 + edge scatter
// blocks [0,GEMM_BLKS): MFMA h1 = x@W1 + attention dots (bf16 out)
// blocks [GEMM_BLKS, ...): scatter edges into XCD-private buckets (hwreg 20 = XCC_ID;
//   correct for ANY xcc in [0,8) — agg sums all 8 segments)
__global__ __launch_bounds__(256) void k_fused1(
    const float* __restrict__ x, const unsigned short* __restrict__ w1t,
    const float* __restrict__ as_w, const float* __restrict__ ad_w,
    unsigned short* __restrict__ hbf, float* __restrict__ as_out, float* __restrict__ ad_out,
    const int* __restrict__ ei, int* __restrict__ cnt, unsigned short* __restrict__ bucket)
{
    __shared__ __align__(16) char sA[64 * 256];   // bf16 [row][k=128], swizzled
    __shared__ __align__(16) char sB[64 * 256];   // bf16 [col][k=128], swizzled
    __shared__ float sAs[64], sAd[64];
    int tid = threadIdx.x;

    if (blockIdx.x >= GEMM_BLKS) {
        // ---------------- scatter path
        int xcc;
        asm("s_getreg_b32 %0, hwreg(20, 0, 32)" : "=s"(xcc));
        xcc &= 7;
        int e = (blockIdx.x - GEMM_BLKS) * 256 + tid;
        if (e >= NE_TOT) return;
        int s, d;
        if (e < E_EDGES) { s = ei[e]; d = ei[E_EDGES + e]; }
        else { s = d = e - E_EDGES; }              // self loop
        int pos = atomicAdd(&cnt[xcc * N_NODES + d], 1);
        if (pos < CAP_X) bucket[((size_t)(xcc * CAP_X + pos)) * N_NODES + d] = (unsigned short)s;
        return;
    }

    // ---------------- GEMM path
    int row0 = blockIdx.x * 64;
#pragma unroll
    for (int i = 0; i < 8; ++i) {                  // 2048 float4 (rows = 32 x 8B chunks)
        int idx = i * 256 + tid;
        int r = idx >> 5, c4 = idx & 31;
        int gr = row0 + r; if (gr >= N_NODES) gr = N_NODES - 1;
        float4 v = ((const float4*)(x + (size_t)gr * IND))[c4];
        ushort4 b; b.x = f2bf(v.x); b.y = f2bf(v.y); b.z = f2bf(v.z); b.w = f2bf(v.w);
        *(ushort4*)(sA + r * 256 + SWZ(r, c4 * 8)) = b;
    }
#pragma unroll
    for (int i = 0; i < 4; ++i) {                  // 1024 x 16B (rows = 16 x 16B chunks)
        int idx = i * 256 + tid;
        int r = idx >> 4, c8 = idx & 15;
        v8s wv = *(const v8s*)(w1t + idx * 8);
        *(v8s*)(sB + r * 256 + SWZ(r, c8 * 16)) = wv;
    }
    if (tid < 64) { sAs[tid] = as_w[tid]; sAd[tid] = ad_w[tid]; }
    __syncthreads();

    int w = tid >> 6, lane = tid & 63;
    int arow = w * 16 + (lane & 15);
    int kb   = (lane >> 4) * 16;
    v4f acc[4] = {};
#pragma unroll
    for (int ks = 0; ks < 4; ++ks) {
        v8s a = *(const v8s*)(sA + arow * 256 + SWZ(arow, ks * 64 + kb));
#pragma unroll
        for (int ct = 0; ct < 4; ++ct) {
            int brow = ct * 16 + (lane & 15);
            v8s b = *(const v8s*)(sB + brow * 256 + SWZ(brow, ks * 64 + kb));
            acc[ct] = __builtin_amdgcn_mfma_f32_16x16x32_bf16(a, b, acc[ct], 0, 0, 0);
        }
    }

    int cbase = lane & 15;
    int rloc  = (lane >> 4) * 4;
#pragma unroll
    for (int ct = 0; ct < 4; ++ct)
#pragma unroll
        for (int rg = 0; rg < 4; ++rg) {
            int row = row0 + w * 16 + rloc + rg;
            if (row < N_NODES) hbf[(size_t)row * 64 + ct * 16 + cbase] = f2bf(acc[ct][rg]);
        }
#pragma unroll
    for (int rg = 0; rg < 4; ++rg) {
        float vs = 0.f, vd = 0.f;
#pragma unroll
        for (int ct = 0; ct < 4; ++ct) {
            vs = fmaf(acc[ct][rg], sAs[ct * 16 + cbase], vs);
            vd = fmaf(acc[ct][rg], sAd[ct * 16 + cbase], vd);
        }
        vs += __shfl_xor(vs, 1, 64); vd += __shfl_xor(vd, 1, 64);
        vs += __shfl_xor(vs, 2, 64); vd += __shfl_xor(vd, 2, 64);
        vs += __shfl_xor(vs, 4, 64); vd += __shfl_xor(vd, 4, 64);
        vs += __shfl_xor(vs, 8, 64); vd += __shfl_xor(vd, 8, 64);
        int row = row0 + w * 16 + rloc + rg;
        if (cbase == 0 && row < N_NODES) { as_out[row] = vs; ad_out[row] = vd; }
    }
}

// ---------------------------------------------------------------- per-dst softmax aggregation
// Weights lane-parallel; accumulate with 4 features/lane (ushort4), 4 rows per
// issue group, 8 rows in flight. 4x fewer load instructions + shuffles than 2B/lane.
template <bool OUT_BF16>
__global__ __launch_bounds__(256) void k_agg(
    const unsigned short* __restrict__ hin, const float* __restrict__ as_, const float* __restrict__ ad_,
    const int* __restrict__ cnt, const unsigned short* __restrict__ bucket,
    const float* __restrict__ bias, void* __restrict__ outv)
{
    int wave = threadIdx.x >> 6, lane = threadIdx.x & 63;
    int n = blockIdx.x * 4 + wave;
    if (n >= N_NODES) return;

    int pref[9]; pref[0] = 0;
#pragma unroll
    for (int xx = 0; xx < 8; ++xx)
        pref[xx + 1] = pref[xx] + min(cnt[xx * N_NODES + n], CAP_X);
    int deg = min(pref[8], 64);

    int xseg = 0, base = 0;
#pragma unroll
    for (int i = 0; i < 7; ++i)
        if (lane >= pref[i + 1]) { xseg = i + 1; base = pref[i + 1]; }

    float adn = ad_[n];
    int s_l = 0;
    float e = -1e30f;
    if (lane < deg) {
        s_l = (int)bucket[((size_t)(xseg * CAP_X + (lane - base))) * N_NODES + n];
        float t = as_[s_l] + adn;
        e = t > 0.f ? t : NEG_SLOPE * t;
    }
    float m = e;
    for (int off = 32; off; off >>= 1) m = fmaxf(m, __shfl_xor(m, off, 64));
    float w_l = (lane < deg) ? __expf(e - m) : 0.f;
    float denom = w_l;
    for (int off = 32; off; off >>= 1) denom += __shfl_xor(denom, off, 64);

    // accumulate: group g = lane>>4 handles rows t+g, t+4+g; features fb..fb+3
    int g = lane >> 4, fb = (lane & 15) * 4;
    float a0 = 0.f, a1 = 0.f, a2 = 0.f, a3 = 0.f;
    for (int t = 0; t < deg; t += 8) {
        int sa = __shfl(s_l, t + g);
        int sb = __shfl(s_l, t + 4 + g);
        float wa = __shfl(w_l, t + g);
        float wb = __shfl(w_l, t + 4 + g);
        ushort4 ha = {0, 0, 0, 0}, hb = {0, 0, 0, 0};
        if (t + g < deg)     ha = *(const ushort4*)(hin + (size_t)sa * HID + fb);
        if (t + 4 + g < deg) hb = *(const ushort4*)(hin + (size_t)sb * HID + fb);
        a0 = fmaf(wa, bf2f(ha.x), a0); a1 = fmaf(wa, bf2f(ha.y), a1);
        a2 = fmaf(wa, bf2f(ha.z), a2); a3 = fmaf(wa, bf2f(ha.w), a3);
        a0 = fmaf(wb, bf2f(hb.x), a0); a1 = fmaf(wb, bf2f(hb.y), a1);
        a2 = fmaf(wb, bf2f(hb.z), a2); a3 = fmaf(wb, bf2f(hb.w), a3);
    }
    a0 += __shfl_xor(a0, 16, 64); a0 += __shfl_xor(a0, 32, 64);
    a1 += __shfl_xor(a1, 16, 64); a1 += __shfl_xor(a1, 32, 64);
    a2 += __shfl_xor(a2, 16, 64); a2 += __shfl_xor(a2, 32, 64);
    a3 += __shfl_xor(a3, 16, 64); a3 += __shfl_xor(a3, 32, 64);

    if (lane < 16) {
        float inv = 1.f / (denom + 1e-16f);
        float4 b4 = ((const float4*)bias)[lane];
        float r0 = fmaf(a0, inv, b4.x), r1 = fmaf(a1, inv, b4.y);
        float r2 = fmaf(a2, inv, b4.z), r3 = fmaf(a3, inv, b4.w);
        if (OUT_BF16) {
            ushort4 o; o.x = f2bf(r0); o.y = f2bf(r1); o.z = f2bf(r2); o.w = f2bf(r3);
            *(ushort4*)((unsigned short*)outv + (size_t)n * HID + lane * 4) = o;
        } else {
            float4 o = {r0, r1, r2, r3};
            *(float4*)((float*)outv + (size_t)n * HID + lane * 4) = o;
        }
    }
}

// ---------------------------------------------------------------- BN statistics (two-stage, bf16 in)
__global__ __launch_bounds__(256) void k_bnstats(const unsigned short* __restrict__ h,
                                                 float* __restrict__ sums) {
    int lane = threadIdx.x & 63, wave = threadIdx.x >> 6;
    float s = 0.f, ss = 0.f;
    for (int r = blockIdx.x * 4 + wave; r < N_NODES; r += gridDim.x * 4) {
        float v = bf2f(h[(size_t)r * HID + lane]);
        s += v; ss = fmaf(v, v, ss);
    }
    __shared__ float ls[4][64], lss[4][64];
    ls[wave][lane] = s; lss[wave][lane] = ss;
    __syncthreads();
    if (wave == 0) {
        s  = ls[0][lane] + ls[1][lane] + ls[2][lane] + ls[3][lane];
        ss = lss[0][lane] + lss[1][lane] + lss[2][lane] + lss[3][lane];
        atomicAdd(&sums[lane], s);
        atomicAdd(&sums[64 + lane], ss);
    }
}

// ---------------------------------------------------------------- GEMM2 (MFMA bf16), BN-final + BN+ReLU fused
__global__ __launch_bounds__(256) void k_gemm2(
    const unsigned short* __restrict__ hin, const unsigned short* __restrict__ w2t,
    const float* __restrict__ sums, const float* __restrict__ gamma, const float* __restrict__ beta,
    const float* __restrict__ as_w, const float* __restrict__ ad_w,
    unsigned short* __restrict__ h2bf, float* __restrict__ as_out, float* __restrict__ ad_out)
{
    __shared__ __align__(16) char sA[64 * 128];   // bf16 [row][k=64], swizzled
    __shared__ __align__(16) char sB[64 * 128];   // bf16 [col][k=64], swizzled
    __shared__ float sAs[64], sAd[64], sScale[64], sShift[64];
    int tid = threadIdx.x;
    int row0 = blockIdx.x * 64;

    if (tid < 64) {                                // fused bnfinal (redundant per block, 3 L2 lines)
        float mean = sums[tid] * (1.f / N_NODES);
        float var  = sums[64 + tid] * (1.f / N_NODES) - mean * mean;
        float sc = gamma[tid] * rsqrtf(var + 1e-5f);
        sScale[tid] = sc;
        sShift[tid] = beta[tid] - mean * sc;
        sAs[tid] = as_w[tid]; sAd[tid] = ad_w[tid];
    }
    __syncthreads();

    // stage input tile (bf16) with BN+ReLU  (rows = 128B = 8 x 16B chunks)
#pragma unroll
    for (int i = 0; i < 2; ++i) {                  // 512 x 16B
        int idx = i * 256 + tid;
        int r = idx >> 3, c8 = idx & 7;
        int gr = row0 + r; if (gr >= N_NODES) gr = N_NODES - 1;
        v8s hv = *(const v8s*)(hin + (size_t)gr * 64 + c8 * 8);
        unsigned short o[8];
#pragma unroll
        for (int j = 0; j < 8; ++j) {
            float f = bf2f((unsigned short)hv[j]);
            o[j] = f2bf(fmaxf(fmaf(f, sScale[c8 * 8 + j], sShift[c8 * 8 + j]), 0.f));
        }
        *(v8s*)(sA + r * 128 + SWZ(r, c8 * 16)) = *(v8s*)o;
    }
#pragma unroll
    for (int i = 0; i < 2; ++i) {                  // 512 x 16B (rows = 8 x 16B chunks)
        int idx = i * 256 + tid;
        int r = idx >> 3, c8 = idx & 7;
        v8s wv = *(const v8s*)(w2t + idx * 8);
        *(v8s*)(sB + r * 128 + SWZ(r, c8 * 16)) = wv;
    }
    __syncthreads();

    int w = tid >> 6, lane = tid & 63;
    int arow = w * 16 + (lane & 15);
    int kb   = (lane >> 4) * 16;
    v4f acc[4] = {};
#pragma unroll
    for (int ks = 0; ks < 2; ++ks) {
        v8s a = *(const v8s*)(sA + arow * 128 + SWZ(arow, ks * 64 + kb));
#pragma unroll
        for (int ct = 0; ct < 4; ++ct) {
            int brow = ct * 16 + (lane & 15);
            v8s b = *(const v8s*)(sB + brow * 128 + SWZ(brow, ks * 64 + kb));
            acc[ct] = __builtin_amdgcn_mfma_f32_16x16x32_bf16(a, b, acc[ct], 0, 0, 0);
        }
    }

    int cbase = lane & 15;
    int rloc  = (lane >> 4) * 4;
#pragma unroll
    for (int ct = 0; ct < 4; ++ct)
#pragma unroll
        for (int rg = 0; rg < 4; ++rg) {
            int row = row0 + w * 16 + rloc + rg;
            if (row < N_NODES) h2bf[(size_t)row * 64 + ct * 16 + cbase] = f2bf(acc[ct][rg]);
        }
#pragma unroll
    for (int rg = 0; rg < 4; ++rg) {
        float vs = 0.f, vd = 0.f;
#pragma unroll
        for (int ct = 0; ct < 4; ++ct) {
            vs = fmaf(acc[ct][rg], sAs[ct * 16 + cbase], vs);
            vd = fmaf(acc[ct][rg], sAd[ct * 16 + cbase], vd);
        }
        vs += __shfl_xor(vs, 1, 64); vd += __shfl_xor(vd, 1, 64);
        vs += __shfl_xor(vs, 2, 64); vd += __shfl_xor(vd, 2, 64);
        vs += __shfl_xor(vs, 4, 64); vd += __shfl_xor(vd, 4, 64);
        vs += __shfl_xor(vs, 8, 64); vd += __shfl_xor(vd, 8, 64);
        int row = row0 + w * 16 + rloc + rg;
        if (cbase == 0 && row < N_NODES) { as_out[row] = vs; ad_out[row] = vd; }
    }
}

// ---------------------------------------------------------------- launch
extern "C" void kernel_launch(void* const* d_in, const int* in_sizes, int n_in,
                              void* d_out, int out_size, void* d_ws, size_t ws_size,
                              hipStream_t stream) {
    const float* x        = (const float*)d_in[0];
    const int*   ei       = (const int*)d_in[1];
    const float* W1       = (const float*)d_in[2];
    const float* att_src1 = (const float*)d_in[3];
    const float* att_dst1 = (const float*)d_in[4];
    const float* bias1    = (const float*)d_in[5];
    const float* gamma    = (const float*)d_in[6];
    const float* beta     = (const float*)d_in[7];
    const float* W2       = (const float*)d_in[8];
    const float* att_src2 = (const float*)d_in[9];
    const float* att_dst2 = (const float*)d_in[10];
    const float* bias2    = (const float*)d_in[11];
    float* out = (float*)d_out;

    char* ws = (char*)d_ws;
    size_t off = 0;
    auto alloc = [&](size_t bytes) { void* p = ws + off; off = (off + bytes + 255) & ~(size_t)255; return p; };
    unsigned short* h1     = (unsigned short*)alloc((size_t)N_NODES * HID * 2);
    float* as1    = (float*)alloc((size_t)N_NODES * 4);
    float* ad1    = (float*)alloc((size_t)N_NODES * 4);
    unsigned short* h1agg  = (unsigned short*)alloc((size_t)N_NODES * HID * 2);
    unsigned short* h2     = (unsigned short*)alloc((size_t)N_NODES * HID * 2);
    float* as2    = (float*)alloc((size_t)N_NODES * 4);
    float* ad2    = (float*)alloc((size_t)N_NODES * 4);
    int*   cnt    = (int*)alloc((size_t)8 * N_NODES * 4);
    unsigned short* bucket = (unsigned short*)alloc((size_t)8 * CAP_X * N_NODES * 2);
    float* sums   = (float*)alloc(128 * 4);
    unsigned short* w1t = (unsigned short*)alloc(64 * IND * 2);
    unsigned short* w2t = (unsigned short*)alloc(64 * 64 * 2);

    int initBlocks = (8 * N_NODES + 255) / 256; // 1563
    k_init<<<initBlocks, 256, 0, stream>>>(W1, W2, cnt, sums, w1t, w2t);
    k_fused1<<<GEMM_BLKS + EDGE_BLKS, 256, 0, stream>>>(x, w1t, att_src1, att_dst1,
                                                        h1, as1, ad1, ei, cnt, bucket);
    k_agg<true><<<(N_NODES + 3) / 4, 256, 0, stream>>>(h1, as1, ad1, cnt, bucket, bias1, h1agg);
    k_bnstats<<<256, 256, 0, stream>>>(h1agg, sums);
    k_gemm2<<<GEMM_BLKS, 256, 0, stream>>>(h1agg, w2t, sums, gamma, beta,
                                           att_src2, att_dst2, h2, as2, ad2);
    k_agg<false><<<(N_NODES + 3) / 4, 256, 0, stream>>>(h2, as2, ad2, cnt, bucket, bias2, out);
}

// Round 10
// 122.897 us; speedup vs baseline: 1.6441x; 1.1184x over previous
//
#include <hip/hip_runtime.h>

#define N_NODES 50000
#define E_EDGES 800000
#define NE_TOT  (E_EDGES + N_NODES)   // edges + self loops = 850000
#define IND     128
#define HID     64
#define CAP_X   32                    // per-XCD slot cap (per-XCD deg ~ Poisson(2.1))
#define NEG_SLOPE 0.2f
#define GEMM_BLKS ((N_NODES + 63) / 64)     // 782
#define EDGE_BLKS ((NE_TOT + 255) / 256)    // 3321

typedef short v8s __attribute__((ext_vector_type(8)));
typedef float v4f __attribute__((ext_vector_type(4)));

// XOR swizzle: spreads stride-256B/128B row reads across 8 16B slots (T2)
#define SWZ(row, byte) ((byte) ^ (((row) & 7) << 4))

static __device__ __forceinline__ unsigned short f2bf(float f) {
    unsigned u = __float_as_uint(f);
    return (unsigned short)((u + 0x7FFF + ((u >> 16) & 1)) >> 16);  // RNE
}
static __device__ __forceinline__ float bf2f(unsigned short u) {
    return __uint_as_float(((unsigned)u) << 16);
}

// ---------------------------------------------------------------- init: zero cnt/sums + prep weights
__global__ void k_init(const float* __restrict__ W1, const float* __restrict__ W2,
                       int* __restrict__ cnt, float* __restrict__ sums,
                       unsigned short* __restrict__ w1t, unsigned short* __restrict__ w2t) {
    int g = blockIdx.x * 256 + threadIdx.x;
    if (g < 8 * N_NODES) cnt[g] = 0;
    if (g < 128) sums[g] = 0.f;
    if (g < 64 * IND) { int c = g >> 7, k = g & 127; w1t[g] = f2bf(W1[k * 64 + c]); }
    if (g < 64 * 64)  { int c = g >> 6, k = g & 63;  w2t[g] = f2bf(W2[k * 64 + c]); }
}

// ---------------------------------------------------------------- fused GEMM1 + edge scatter
__global__ __launch_bounds__(256) void k_fused1(
    const float* __restrict__ x, const unsigned short* __restrict__ w1t,
    const float* __restrict__ as_w, const float* __restrict__ ad_w,
    unsigned short* __restrict__ hbf, float* __restrict__ as_out, float* __restrict__ ad_out,
    const int* __restrict__ ei, int* __restrict__ cnt, unsigned short* __restrict__ bucket)
{
    __shared__ __align__(16) char sA[64 * 256];   // bf16 [row][k=128], swizzled; reused as C-tile
    __shared__ __align__(16) char sB[64 * 256];
    __shared__ float sAs[64], sAd[64];
    int tid = threadIdx.x;

    if (blockIdx.x >= GEMM_BLKS) {
        // ---------------- scatter path (XCD-private buckets; hwreg 20 = XCC_ID)
        int xcc;
        asm("s_getreg_b32 %0, hwreg(20, 0, 32)" : "=s"(xcc));
        xcc &= 7;
        int e = (blockIdx.x - GEMM_BLKS) * 256 + tid;
        if (e >= NE_TOT) return;
        int s, d;
        if (e < E_EDGES) { s = ei[e]; d = ei[E_EDGES + e]; }
        else { s = d = e - E_EDGES; }              // self loop
        int pos = atomicAdd(&cnt[xcc * N_NODES + d], 1);
        if (pos < CAP_X) bucket[((size_t)(xcc * CAP_X + pos)) * N_NODES + d] = (unsigned short)s;
        return;
    }

    // ---------------- GEMM path
    int row0 = blockIdx.x * 64;
#pragma unroll
    for (int i = 0; i < 8; ++i) {                  // 2048 float4 (rows = 32 x 8B chunks)
        int idx = i * 256 + tid;
        int r = idx >> 5, c4 = idx & 31;
        int gr = row0 + r; if (gr >= N_NODES) gr = N_NODES - 1;
        float4 v = ((const float4*)(x + (size_t)gr * IND))[c4];
        ushort4 b; b.x = f2bf(v.x); b.y = f2bf(v.y); b.z = f2bf(v.z); b.w = f2bf(v.w);
        *(ushort4*)(sA + r * 256 + SWZ(r, c4 * 8)) = b;
    }
#pragma unroll
    for (int i = 0; i < 4; ++i) {                  // 1024 x 16B (rows = 16 x 16B chunks)
        int idx = i * 256 + tid;
        int r = idx >> 4, c8 = idx & 15;
        v8s wv = *(const v8s*)(w1t + idx * 8);
        *(v8s*)(sB + r * 256 + SWZ(r, c8 * 16)) = wv;
    }
    if (tid < 64) { sAs[tid] = as_w[tid]; sAd[tid] = ad_w[tid]; }
    __syncthreads();

    int w = tid >> 6, lane = tid & 63;
    int arow = w * 16 + (lane & 15);
    int kb   = (lane >> 4) * 16;
    v4f acc[4] = {};
#pragma unroll
    for (int ks = 0; ks < 4; ++ks) {
        v8s a = *(const v8s*)(sA + arow * 256 + SWZ(arow, ks * 64 + kb));
#pragma unroll
        for (int ct = 0; ct < 4; ++ct) {
            int brow = ct * 16 + (lane & 15);
            v8s b = *(const v8s*)(sB + brow * 256 + SWZ(brow, ks * 64 + kb));
            acc[ct] = __builtin_amdgcn_mfma_f32_16x16x32_bf16(a, b, acc[ct], 0, 0, 0);
        }
    }

    int cbase = lane & 15;
    int rloc  = (lane >> 4) * 4;
    // attention dots (register-only)
#pragma unroll
    for (int rg = 0; rg < 4; ++rg) {
        float vs = 0.f, vd = 0.f;
#pragma unroll
        for (int ct = 0; ct < 4; ++ct) {
            vs = fmaf(acc[ct][rg], sAs[ct * 16 + cbase], vs);
            vd = fmaf(acc[ct][rg], sAd[ct * 16 + cbase], vd);
        }
        vs += __shfl_xor(vs, 1, 64); vd += __shfl_xor(vd, 1, 64);
        vs += __shfl_xor(vs, 2, 64); vd += __shfl_xor(vd, 2, 64);
        vs += __shfl_xor(vs, 4, 64); vd += __shfl_xor(vd, 4, 64);
        vs += __shfl_xor(vs, 8, 64); vd += __shfl_xor(vd, 8, 64);
        int row = row0 + w * 16 + rloc + rg;
        if (cbase == 0 && row < N_NODES) { as_out[row] = vs; ad_out[row] = vd; }
    }
    // coalesced h store: repack via LDS (reuse sA)
    __syncthreads();
    unsigned short* sC = (unsigned short*)sA;      // [64][64] bf16 = 8KB
#pragma unroll
    for (int ct = 0; ct < 4; ++ct)
#pragma unroll
        for (int rg = 0; rg < 4; ++rg)
            sC[(w * 16 + rloc + rg) * 64 + ct * 16 + cbase] = f2bf(acc[ct][rg]);
    __syncthreads();
    int validc = min(64, N_NODES - row0) * 8;      // 16B chunks
#pragma unroll
    for (int i = 0; i < 2; ++i) {
        int c = i * 256 + tid;
        if (c < validc)
            *(v8s*)(hbf + (size_t)row0 * 64 + c * 8) = *(const v8s*)(sC + c * 8);
    }
}

// ---------------------------------------------------------------- per-dst softmax aggregation
// 2 nodes per wave, time-multiplexed: independent chains interleaved for 2x MLP.
template <bool OUT_BF16>
__global__ __launch_bounds__(256) void k_agg(
    const unsigned short* __restrict__ hin, const float* __restrict__ as_, const float* __restrict__ ad_,
    const int* __restrict__ cnt, const unsigned short* __restrict__ bucket,
    const float* __restrict__ bias, void* __restrict__ outv)
{
    int wave = threadIdx.x >> 6, lane = threadIdx.x & 63;
    int n0 = blockIdx.x * 8 + wave * 2;            // 6250 blocks x 8 nodes = 50000 exact

    int deg[2], xseg[2], base[2], s_l[2];
    float e_[2], m_[2], w_l[2], denom[2];

#pragma unroll
    for (int j = 0; j < 2; ++j) {
        int n = n0 + j;
        int p[9]; p[0] = 0;
#pragma unroll
        for (int xx = 0; xx < 8; ++xx)
            p[xx + 1] = p[xx] + min(cnt[xx * N_NODES + n], CAP_X);
        deg[j] = min(p[8], 64);
        int xs = 0, bs = 0;
#pragma unroll
        for (int i = 0; i < 7; ++i)
            if (lane >= p[i + 1]) { xs = i + 1; bs = p[i + 1]; }
        xseg[j] = xs; base[j] = bs;
    }
#pragma unroll
    for (int j = 0; j < 2; ++j) {
        s_l[j] = 0; e_[j] = -1e30f;
        if (lane < deg[j]) {
            s_l[j] = (int)bucket[((size_t)(xseg[j] * CAP_X + (lane - base[j]))) * N_NODES + n0 + j];
            float t = as_[s_l[j]] + ad_[n0 + j];
            e_[j] = t > 0.f ? t : NEG_SLOPE * t;
        }
        m_[j] = e_[j];
    }
    for (int off = 32; off; off >>= 1) {
        m_[0] = fmaxf(m_[0], __shfl_xor(m_[0], off, 64));
        m_[1] = fmaxf(m_[1], __shfl_xor(m_[1], off, 64));
    }
#pragma unroll
    for (int j = 0; j < 2; ++j) {
        w_l[j] = (lane < deg[j]) ? __expf(e_[j] - m_[j]) : 0.f;
        denom[j] = w_l[j];
    }
    for (int off = 32; off; off >>= 1) {
        denom[0] += __shfl_xor(denom[0], off, 64);
        denom[1] += __shfl_xor(denom[1], off, 64);
    }

    // accumulate: group g handles rows t+g, t+4+g for both nodes (4 loads in flight)
    // loads unconditional: idle-lane w = 0 kills bogus contributions (s_l=0 is a valid row)
    int g = lane >> 4, fb = (lane & 15) * 4;
    float a[2][4] = {};
    int dmax = max(deg[0], deg[1]);
    for (int t = 0; t < dmax; t += 8) {
#pragma unroll
        for (int j = 0; j < 2; ++j) {
            int sa = __shfl(s_l[j], t + g);
            int sb = __shfl(s_l[j], t + 4 + g);
            float wa = __shfl(w_l[j], t + g);
            float wb = __shfl(w_l[j], t + 4 + g);
            ushort4 ha = *(const ushort4*)(hin + (size_t)sa * HID + fb);
            ushort4 hb = *(const ushort4*)(hin + (size_t)sb * HID + fb);
            a[j][0] = fmaf(wa, bf2f(ha.x), a[j][0]); a[j][1] = fmaf(wa, bf2f(ha.y), a[j][1]);
            a[j][2] = fmaf(wa, bf2f(ha.z), a[j][2]); a[j][3] = fmaf(wa, bf2f(ha.w), a[j][3]);
            a[j][0] = fmaf(wb, bf2f(hb.x), a[j][0]); a[j][1] = fmaf(wb, bf2f(hb.y), a[j][1]);
            a[j][2] = fmaf(wb, bf2f(hb.z), a[j][2]); a[j][3] = fmaf(wb, bf2f(hb.w), a[j][3]);
        }
    }
#pragma unroll
    for (int j = 0; j < 2; ++j)
#pragma unroll
        for (int k = 0; k < 4; ++k) {
            a[j][k] += __shfl_xor(a[j][k], 16, 64);
            a[j][k] += __shfl_xor(a[j][k], 32, 64);
        }

    if (lane < 16) {
        float4 b4 = ((const float4*)bias)[lane];
#pragma unroll
        for (int j = 0; j < 2; ++j) {
            float inv = 1.f / (denom[j] + 1e-16f);
            float r0 = fmaf(a[j][0], inv, b4.x), r1 = fmaf(a[j][1], inv, b4.y);
            float r2 = fmaf(a[j][2], inv, b4.z), r3 = fmaf(a[j][3], inv, b4.w);
            if (OUT_BF16) {
                ushort4 o; o.x = f2bf(r0); o.y = f2bf(r1); o.z = f2bf(r2); o.w = f2bf(r3);
                *(ushort4*)((unsigned short*)outv + (size_t)(n0 + j) * HID + lane * 4) = o;
            } else {
                float4 o = {r0, r1, r2, r3};
                *(float4*)((float*)outv + (size_t)(n0 + j) * HID + lane * 4) = o;
            }
        }
    }
}

// ---------------------------------------------------------------- BN statistics (two-stage, bf16 in)
__global__ __launch_bounds__(256) void k_bnstats(const unsigned short* __restrict__ h,
                                                 float* __restrict__ sums) {
    int lane = threadIdx.x & 63, wave = threadIdx.x >> 6;
    float s = 0.f, ss = 0.f;
    for (int r = blockIdx.x * 4 + wave; r < N_NODES; r += gridDim.x * 4) {
        float v = bf2f(h[(size_t)r * HID + lane]);
        s += v; ss = fmaf(v, v, ss);
    }
    __shared__ float ls[4][64], lss[4][64];
    ls[wave][lane] = s; lss[wave][lane] = ss;
    __syncthreads();
    if (wave == 0) {
        s  = ls[0][lane] + ls[1][lane] + ls[2][lane] + ls[3][lane];
        ss = lss[0][lane] + lss[1][lane] + lss[2][lane] + lss[3][lane];
        atomicAdd(&sums[lane], s);
        atomicAdd(&sums[64 + lane], ss);
    }
}

// ---------------------------------------------------------------- GEMM2 (MFMA bf16), BN-final + BN+ReLU fused
__global__ __launch_bounds__(256) void k_gemm2(
    const unsigned short* __restrict__ hin, const unsigned short* __restrict__ w2t,
    const float* __restrict__ sums, const float* __restrict__ gamma, const float* __restrict__ beta,
    const float* __restrict__ as_w, const float* __restrict__ ad_w,
    unsigned short* __restrict__ h2bf, float* __restrict__ as_out, float* __restrict__ ad_out)
{
    __shared__ __align__(16) char sA[64 * 128];   // bf16 [row][k=64], swizzled; reused as C-tile
    __shared__ __align__(16) char sB[64 * 128];
    __shared__ float sAs[64], sAd[64], sScale[64], sShift[64];
    int tid = threadIdx.x;
    int row0 = blockIdx.x * 64;

    if (tid < 64) {                                // fused bnfinal
        float mean = sums[tid] * (1.f / N_NODES);
        float var  = sums[64 + tid] * (1.f / N_NODES) - mean * mean;
        float sc = gamma[tid] * rsqrtf(var + 1e-5f);
        sScale[tid] = sc;
        sShift[tid] = beta[tid] - mean * sc;
        sAs[tid] = as_w[tid]; sAd[tid] = ad_w[tid];
    }
    __syncthreads();

#pragma unroll
    for (int i = 0; i < 2; ++i) {                  // 512 x 16B (rows = 8 x 16B chunks)
        int idx = i * 256 + tid;
        int r = idx >> 3, c8 = idx & 7;
        int gr = row0 + r; if (gr >= N_NODES) gr = N_NODES - 1;
        v8s hv = *(const v8s*)(hin + (size_t)gr * 64 + c8 * 8);
        unsigned short o[8];
#pragma unroll
        for (int j = 0; j < 8; ++j) {
            float f = bf2f((unsigned short)hv[j]);
            o[j] = f2bf(fmaxf(fmaf(f, sScale[c8 * 8 + j], sShift[c8 * 8 + j]), 0.f));
        }
        *(v8s*)(sA + r * 128 + SWZ(r, c8 * 16)) = *(v8s*)o;
    }
#pragma unroll
    for (int i = 0; i < 2; ++i) {
        int idx = i * 256 + tid;
        int r = idx >> 3, c8 = idx & 7;
        v8s wv = *(const v8s*)(w2t + idx * 8);
        *(v8s*)(sB + r * 128 + SWZ(r, c8 * 16)) = wv;
    }
    __syncthreads();

    int w = tid >> 6, lane = tid & 63;
    int arow = w * 16 + (lane & 15);
    int kb   = (lane >> 4) * 16;
    v4f acc[4] = {};
#pragma unroll
    for (int ks = 0; ks < 2; ++ks) {
        v8s a = *(const v8s*)(sA + arow * 128 + SWZ(arow, ks * 64 + kb));
#pragma unroll
        for (int ct = 0; ct < 4; ++ct) {
            int brow = ct * 16 + (lane & 15);
            v8s b = *(const v8s*)(sB + brow * 128 + SWZ(brow, ks * 64 + kb));
            acc[ct] = __builtin_amdgcn_mfma_f32_16x16x32_bf16(a, b, acc[ct], 0, 0, 0);
        }
    }

    int cbase = lane & 15;
    int rloc  = (lane >> 4) * 4;
#pragma unroll
    for (int rg = 0; rg < 4; ++rg) {
        float vs = 0.f, vd = 0.f;
#pragma unroll
        for (int ct = 0; ct < 4; ++ct) {
            vs = fmaf(acc[ct][rg], sAs[ct * 16 + cbase], vs);
            vd = fmaf(acc[ct][rg], sAd[ct * 16 + cbase], vd);
        }
        vs += __shfl_xor(vs, 1, 64); vd += __shfl_xor(vd, 1, 64);
        vs += __shfl_xor(vs, 2, 64); vd += __shfl_xor(vd, 2, 64);
        vs += __shfl_xor(vs, 4, 64); vd += __shfl_xor(vd, 4, 64);
        vs += __shfl_xor(vs, 8, 64); vd += __shfl_xor(vd, 8, 64);
        int row = row0 + w * 16 + rloc + rg;
        if (cbase == 0 && row < N_NODES) { as_out[row] = vs; ad_out[row] = vd; }
    }
    // coalesced h2 store via LDS repack
    __syncthreads();
    unsigned short* sC = (unsigned short*)sA;      // [64][64] bf16 = 8KB
#pragma unroll
    for (int ct = 0; ct < 4; ++ct)
#pragma unroll
        for (int rg = 0; rg < 4; ++rg)
            sC[(w * 16 + rloc + rg) * 64 + ct * 16 + cbase] = f2bf(acc[ct][rg]);
    __syncthreads();
    int validc = min(64, N_NODES - row0) * 8;
#pragma unroll
    for (int i = 0; i < 2; ++i) {
        int c = i * 256 + tid;
        if (c < validc)
            *(v8s*)(h2bf + (size_t)row0 * 64 + c * 8) = *(const v8s*)(sC + c * 8);
    }
}

// ---------------------------------------------------------------- launch
extern "C" void kernel_launch(void* const* d_in, const int* in_sizes, int n_in,
                              void* d_out, int out_size, void* d_ws, size_t ws_size,
                              hipStream_t stream) {
    const float* x        = (const float*)d_in[0];
    const int*   ei       = (const int*)d_in[1];
    const float* W1       = (const float*)d_in[2];
    const float* att_src1 = (const float*)d_in[3];
    const float* att_dst1 = (const float*)d_in[4];
    const float* bias1    = (const float*)d_in[5];
    const float* gamma    = (const float*)d_in[6];
    const float* beta     = (const float*)d_in[7];
    const float* W2       = (const float*)d_in[8];
    const float* att_src2 = (const float*)d_in[9];
    const float* att_dst2 = (const float*)d_in[10];
    const float* bias2    = (const float*)d_in[11];
    float* out = (float*)d_out;

    char* ws = (char*)d_ws;
    size_t off = 0;
    auto alloc = [&](size_t bytes) { void* p = ws + off; off = (off + bytes + 255) & ~(size_t)255; return p; };
    unsigned short* h1     = (unsigned short*)alloc((size_t)N_NODES * HID * 2);
    float* as1    = (float*)alloc((size_t)N_NODES * 4);
    float* ad1    = (float*)alloc((size_t)N_NODES * 4);
    unsigned short* h1agg  = (unsigned short*)alloc((size_t)N_NODES * HID * 2);
    unsigned short* h2     = (unsigned short*)alloc((size_t)N_NODES * HID * 2);
    float* as2    = (float*)alloc((size_t)N_NODES * 4);
    float* ad2    = (float*)alloc((size_t)N_NODES * 4);
    int*   cnt    = (int*)alloc((size_t)8 * N_NODES * 4);
    unsigned short* bucket = (unsigned short*)alloc((size_t)8 * CAP_X * N_NODES * 2);
    float* sums   = (float*)alloc(128 * 4);
    unsigned short* w1t = (unsigned short*)alloc(64 * IND * 2);
    unsigned short* w2t = (unsigned short*)alloc(64 * 64 * 2);

    int initBlocks = (8 * N_NODES + 255) / 256; // 1563
    k_init<<<initBlocks, 256, 0, stream>>>(W1, W2, cnt, sums, w1t, w2t);
    k_fused1<<<GEMM_BLKS + EDGE_BLKS, 256, 0, stream>>>(x, w1t, att_src1, att_dst1,
                                                        h1, as1, ad1, ei, cnt, bucket);
    k_agg<true><<<N_NODES / 8, 256, 0, stream>>>(h1, as1, ad1, cnt, bucket, bias1, h1agg);
    k_bnstats<<<256, 256, 0, stream>>>(h1agg, sums);
    k_gemm2<<<GEMM_BLKS, 256, 0, stream>>>(h1agg, w2t, sums, gamma, beta,
                                           att_src2, att_dst2, h2, as2, ad2);
    k_agg<false><<<N_NODES / 8, 256, 0, stream>>>(h2, as2, ad2, cnt, bucket, bias2, out);
}